// Round 5
// baseline (347.926 us; speedup 1.0000x reference)
//
#include <hip/hip_runtime.h>

#define DF 128
#define AST 136   // padded LDS row stride (bf16 elems)
#define EPB 2048  // edges per block in bucket passes

typedef float f32x4 __attribute__((ext_vector_type(4)));
typedef short bf16x8 __attribute__((ext_vector_type(8)));

__device__ __forceinline__ ushort f2bf(float f) {
  union { float f; uint u; } c; c.f = f;
  uint u = c.u;
  uint r = (u + 0x7fffu + ((u >> 16) & 1u)) >> 16;   // RNE
  return (ushort)r;
}
__device__ __forceinline__ float bf_lo(uint v) { union { uint u; float f; } c; c.u = v << 16; return c.f; }
__device__ __forceinline__ float bf_hi(uint v) { union { uint u; float f; } c; c.u = v & 0xffff0000u; return c.f; }

// ---------------- prep: convert x to bf16, transpose W1/W2/W3 to bf16 ----------------
__global__ void prep_kernel(const float* __restrict__ x, ushort* __restrict__ xb,
                            const float* __restrict__ W1, ushort* __restrict__ Wt1,
                            const float* __restrict__ W2, ushort* __restrict__ Wt2,
                            const float* __restrict__ W3, ushort* __restrict__ W3t, int n4) {
  int i = blockIdx.x * 256 + threadIdx.x;
  if (i < n4) {
    float4 v = ((const float4*)x)[i];
    ushort4 o; o.x = f2bf(v.x); o.y = f2bf(v.y); o.z = f2bf(v.z); o.w = f2bf(v.w);
    ((ushort4*)xb)[i] = o;
    return;
  }
  int j = i - n4;
  if (j < DF * DF) {
    int nr = j >> 7, k = j & 127;
    Wt1[j] = f2bf(W1[(size_t)k * DF + nr]);
    return;
  }
  j -= DF * DF;
  if (j < DF * DF) {
    int nr = j >> 7, k = j & 127;
    Wt2[j] = f2bf(W2[(size_t)k * DF + nr]);
    return;
  }
  j -= DF * DF;
  if (j < 16 * DF) {
    int nr = j >> 7, k = j & 127;
    W3t[j] = (nr < 10) ? f2bf(W3[(size_t)k * 10 + nr]) : (ushort)0;
  }
}

// ---------------- CSR build: two-level counting sort (bucket = dst >> 8) ----------------

__global__ void bucket_hist_kernel(const int* __restrict__ dst, int* __restrict__ histG,
                                   int E, int nbuck, int nblocks) {
  extern __shared__ int lh[];
  int tid = threadIdx.x, blk = blockIdx.x;
  for (int i = tid; i < nbuck; i += 256) lh[i] = 0;
  __syncthreads();
  int base = blk * EPB;
#pragma unroll
  for (int it = 0; it < EPB / 256; ++it) {
    int e = base + it * 256 + tid;
    if (e < E) atomicAdd(&lh[dst[e] >> 8], 1);
  }
  __syncthreads();
  for (int i = tid; i < nbuck; i += 256) histG[(size_t)i * nblocks + blk] = lh[i];
}

// generic scan, 1024 elems/block
__global__ void scan1_kernel(const int* __restrict__ cnt, int* __restrict__ excl,
                             int* __restrict__ bsums, int n) {
  __shared__ int wsum[4];
  int t = threadIdx.x;
  int base = blockIdx.x * 1024 + t * 4;
  int v[4]; int s = 0;
#pragma unroll
  for (int i = 0; i < 4; i++) { int d = (base + i < n) ? cnt[base + i] : 0; v[i] = s; s += d; }
  int lane = t & 63, w = t >> 6;
  int sc = s;
#pragma unroll
  for (int off = 1; off < 64; off <<= 1) { int o = __shfl_up(sc, off); if (lane >= off) sc += o; }
  if (lane == 63) wsum[w] = sc;
  __syncthreads();
  int woff = 0;
  for (int i = 0; i < w; i++) woff += wsum[i];
  int toff = woff + (sc - s);
#pragma unroll
  for (int i = 0; i < 4; i++) if (base + i < n) excl[base + i] = toff + v[i];
  if (t == 255) bsums[blockIdx.x] = woff + sc;
}

// single-block exclusive scan for up to 1024 block-sums (wave-parallel)
__global__ void scan2_kernel(int* bsums, int nb) {
  __shared__ int wsum[16];
  int t = threadIdx.x;
  int v = (t < nb) ? bsums[t] : 0;
  int lane = t & 63, w = t >> 6;
  int sc = v;
#pragma unroll
  for (int off = 1; off < 64; off <<= 1) { int o = __shfl_up(sc, off); if (lane >= off) sc += o; }
  if (lane == 63) wsum[w] = sc;
  __syncthreads();
  int woff = 0;
  for (int i = 0; i < w; i++) woff += wsum[i];
  if (t < nb) bsums[t] = woff + sc - v;
}

// scatter edges into bucket-contiguous packed array: src | (dst&255)<<24
__global__ void bucket_scatter_kernel(const int* __restrict__ src, const int* __restrict__ dst,
                                      const int* __restrict__ histE, const int* __restrict__ bsums,
                                      uint* __restrict__ eb, int E, int nbuck, int nblocks) {
  extern __shared__ int lc[];
  int tid = threadIdx.x, blk = blockIdx.x;
  for (int i = tid; i < nbuck; i += 256) {
    int idx = i * nblocks + blk;
    lc[i] = histE[idx] + bsums[idx >> 10];
  }
  __syncthreads();
  int base = blk * EPB;
#pragma unroll
  for (int it = 0; it < EPB / 256; ++it) {
    int e = base + it * 256 + tid;
    if (e < E) {
      int d = dst[e];
      int pos = atomicAdd(&lc[d >> 8], 1);
      eb[pos] = (uint)src[e] | ((uint)(d & 255) << 24);
    }
  }
}

// one block per bucket: counting sort over 256 nodes, emit rowptr + csr
__global__ void bucket_sort_kernel(const uint* __restrict__ eb,
                                   const int* __restrict__ histE, const int* __restrict__ bsums,
                                   int* __restrict__ rowptr, int* __restrict__ csr,
                                   int N, int E, int nbuck, int nblocks) {
  __shared__ int cnt[256];
  __shared__ int cursor[256];
  __shared__ int wsum[4];
  int tid = threadIdx.x, b = blockIdx.x;
  int idx = b * nblocks;
  int beg = histE[idx] + bsums[idx >> 10];
  int end = E;
  if (b + 1 < nbuck) { int i2 = (b + 1) * nblocks; end = histE[i2] + bsums[i2 >> 10]; }
  cnt[tid] = 0;
  __syncthreads();
  for (int e = beg + tid; e < end; e += 256)
    atomicAdd(&cnt[eb[e] >> 24], 1);
  __syncthreads();
  int v = cnt[tid];
  int lane = tid & 63, w = tid >> 6;
  int sc = v;
#pragma unroll
  for (int off = 1; off < 64; off <<= 1) { int o = __shfl_up(sc, off); if (lane >= off) sc += o; }
  if (lane == 63) wsum[w] = sc;
  __syncthreads();
  int woff = 0;
  for (int i = 0; i < w; i++) woff += wsum[i];
  int excl = woff + sc - v;
  int node = (b << 8) + tid;
  if (node <= N) rowptr[node] = beg + excl;
  cursor[tid] = beg + excl;
  __syncthreads();
  for (int e = beg + tid; e < end; e += 256) {
    uint vv = eb[e];
    int pos = atomicAdd(&cursor[vv >> 24], 1);
    csr[pos] = (int)(vv & 0x00FFFFFFu);
  }
}

// ---------------- fused: aggregate 64 nodes -> LDS -> MFMA x W + bias + tanh ----------------
// 4 waves; wave w pools nodes [w*16, w*16+16) (pooling averages degree variance).
// W read directly from global (32KB, L1-resident) as B-fragments.
__global__ __launch_bounds__(256) void fused_layer_kernel(
    const ushort* __restrict__ in, const int* __restrict__ rowptr,
    const int* __restrict__ csr, const ushort* __restrict__ Wt,
    const float* __restrict__ bias, ushort* __restrict__ out, int n) {
  __shared__ ushort As[64 * AST];
  int tid = threadIdx.x;
  int lane = tid & 63, w = tid >> 6;
  int node0 = blockIdx.x * 64;
  const uint* x2 = (const uint*)in;

  for (int r = 0; r < 16; ++r) {
    int row = w * 16 + r;
    int node = node0 + row;
    uint packed = 0;
    if (node < n) {
      int beg = rowptr[node], end = rowptr[node + 1];
      float ax = 0.f, ay = 0.f;
      int e = beg;
      for (; e + 8 <= end; e += 8) {
        uint v0 = x2[(size_t)csr[e]     * 64 + lane];
        uint v1 = x2[(size_t)csr[e + 1] * 64 + lane];
        uint v2 = x2[(size_t)csr[e + 2] * 64 + lane];
        uint v3 = x2[(size_t)csr[e + 3] * 64 + lane];
        uint v4 = x2[(size_t)csr[e + 4] * 64 + lane];
        uint v5 = x2[(size_t)csr[e + 5] * 64 + lane];
        uint v6 = x2[(size_t)csr[e + 6] * 64 + lane];
        uint v7 = x2[(size_t)csr[e + 7] * 64 + lane];
        ax += (bf_lo(v0) + bf_lo(v1)) + (bf_lo(v2) + bf_lo(v3)) + (bf_lo(v4) + bf_lo(v5)) + (bf_lo(v6) + bf_lo(v7));
        ay += (bf_hi(v0) + bf_hi(v1)) + (bf_hi(v2) + bf_hi(v3)) + (bf_hi(v4) + bf_hi(v5)) + (bf_hi(v6) + bf_hi(v7));
      }
      for (; e < end; ++e) {
        uint vv = x2[(size_t)csr[e] * 64 + lane];
        ax += bf_lo(vv); ay += bf_hi(vv);
      }
      int deg = end - beg;
      if (deg > 0) {
        float inv = 1.0f / (float)deg;
        packed = (uint)f2bf(ax * inv) | ((uint)f2bf(ay * inv) << 16);
      } else {
        packed = x2[(size_t)node * 64 + lane];
      }
    }
    *(uint*)&As[row * AST + 2 * lane] = packed;
  }
  __syncthreads();

  int wr = (w >> 1) * 32, wc = (w & 1) * 64;
  int r16 = lane & 15, g8 = (lane >> 4) * 8;
  f32x4 acc[2][4];
#pragma unroll
  for (int i = 0; i < 2; i++)
#pragma unroll
    for (int j = 0; j < 4; j++) acc[i][j] = (f32x4){0.f, 0.f, 0.f, 0.f};

#pragma unroll
  for (int ks = 0; ks < 4; ++ks) {
    int k0 = ks * 32 + g8;
    bf16x8 a0 = *(const bf16x8*)&As[(wr + r16) * AST + k0];
    bf16x8 a1 = *(const bf16x8*)&As[(wr + 16 + r16) * AST + k0];
#pragma unroll
    for (int j = 0; j < 4; ++j) {
      bf16x8 b = *(const bf16x8*)&Wt[(size_t)(wc + j * 16 + r16) * DF + k0];
      acc[0][j] = __builtin_amdgcn_mfma_f32_16x16x32_bf16(a0, b, acc[0][j], 0, 0, 0);
      acc[1][j] = __builtin_amdgcn_mfma_f32_16x16x32_bf16(a1, b, acc[1][j], 0, 0, 0);
    }
  }

#pragma unroll
  for (int mi = 0; mi < 2; mi++) {
#pragma unroll
    for (int j = 0; j < 4; j++) {
      int col = wc + j * 16 + r16;
      float bv = bias[col];
      int rowb = wr + mi * 16 + (lane >> 4) * 4;
#pragma unroll
      for (int q = 0; q < 4; q++) {
        int node = node0 + rowb + q;
        if (node < n) out[(size_t)node * DF + col] = f2bf(tanhf(acc[mi][j][q] + bv));
      }
    }
  }
}

// ---------------- fused layer2 + head: aggregate -> MFMA xW2 + tanh -> LDS -> MFMA xW3 -> f32 out
__global__ __launch_bounds__(256) void fused_layer_head_kernel(
    const ushort* __restrict__ in, const int* __restrict__ rowptr,
    const int* __restrict__ csr, const ushort* __restrict__ Wt,
    const float* __restrict__ bias, const ushort* __restrict__ W3t,
    const float* __restrict__ b3, float* __restrict__ out, int n) {
  __shared__ ushort As[64 * AST];
  int tid = threadIdx.x;
  int lane = tid & 63, w = tid >> 6;
  int node0 = blockIdx.x * 64;
  const uint* x2 = (const uint*)in;

  for (int r = 0; r < 16; ++r) {
    int row = w * 16 + r;
    int node = node0 + row;
    uint packed = 0;
    if (node < n) {
      int beg = rowptr[node], end = rowptr[node + 1];
      float ax = 0.f, ay = 0.f;
      int e = beg;
      for (; e + 8 <= end; e += 8) {
        uint v0 = x2[(size_t)csr[e]     * 64 + lane];
        uint v1 = x2[(size_t)csr[e + 1] * 64 + lane];
        uint v2 = x2[(size_t)csr[e + 2] * 64 + lane];
        uint v3 = x2[(size_t)csr[e + 3] * 64 + lane];
        uint v4 = x2[(size_t)csr[e + 4] * 64 + lane];
        uint v5 = x2[(size_t)csr[e + 5] * 64 + lane];
        uint v6 = x2[(size_t)csr[e + 6] * 64 + lane];
        uint v7 = x2[(size_t)csr[e + 7] * 64 + lane];
        ax += (bf_lo(v0) + bf_lo(v1)) + (bf_lo(v2) + bf_lo(v3)) + (bf_lo(v4) + bf_lo(v5)) + (bf_lo(v6) + bf_lo(v7));
        ay += (bf_hi(v0) + bf_hi(v1)) + (bf_hi(v2) + bf_hi(v3)) + (bf_hi(v4) + bf_hi(v5)) + (bf_hi(v6) + bf_hi(v7));
      }
      for (; e < end; ++e) {
        uint vv = x2[(size_t)csr[e] * 64 + lane];
        ax += bf_lo(vv); ay += bf_hi(vv);
      }
      int deg = end - beg;
      if (deg > 0) {
        float inv = 1.0f / (float)deg;
        packed = (uint)f2bf(ax * inv) | ((uint)f2bf(ay * inv) << 16);
      } else {
        packed = x2[(size_t)node * 64 + lane];
      }
    }
    *(uint*)&As[row * AST + 2 * lane] = packed;
  }
  __syncthreads();

  int wr = (w >> 1) * 32, wc = (w & 1) * 64;
  int r16 = lane & 15, g8 = (lane >> 4) * 8;
  f32x4 acc[2][4];
#pragma unroll
  for (int i = 0; i < 2; i++)
#pragma unroll
    for (int j = 0; j < 4; j++) acc[i][j] = (f32x4){0.f, 0.f, 0.f, 0.f};

#pragma unroll
  for (int ks = 0; ks < 4; ++ks) {
    int k0 = ks * 32 + g8;
    bf16x8 a0 = *(const bf16x8*)&As[(wr + r16) * AST + k0];
    bf16x8 a1 = *(const bf16x8*)&As[(wr + 16 + r16) * AST + k0];
#pragma unroll
    for (int j = 0; j < 4; ++j) {
      bf16x8 b = *(const bf16x8*)&Wt[(size_t)(wc + j * 16 + r16) * DF + k0];
      acc[0][j] = __builtin_amdgcn_mfma_f32_16x16x32_bf16(a0, b, acc[0][j], 0, 0, 0);
      acc[1][j] = __builtin_amdgcn_mfma_f32_16x16x32_bf16(a1, b, acc[1][j], 0, 0, 0);
    }
  }

  __syncthreads();   // all As reads done; safe to overwrite with h2
#pragma unroll
  for (int mi = 0; mi < 2; mi++) {
#pragma unroll
    for (int j = 0; j < 4; j++) {
      int col = wc + j * 16 + r16;
      float bv = bias[col];
      int rowb = wr + mi * 16 + (lane >> 4) * 4;
#pragma unroll
      for (int q = 0; q < 4; q++)
        As[(rowb + q) * AST + col] = f2bf(tanhf(acc[mi][j][q] + bv));
    }
  }
  __syncthreads();

  // head: wave w handles rows [w*16, w*16+16)
  f32x4 h = (f32x4){0.f, 0.f, 0.f, 0.f};
#pragma unroll
  for (int ks = 0; ks < 4; ++ks) {
    int k0 = ks * 32 + g8;
    bf16x8 a = *(const bf16x8*)&As[(w * 16 + r16) * AST + k0];
    bf16x8 b = *(const bf16x8*)&W3t[(size_t)r16 * DF + k0];
    h = __builtin_amdgcn_mfma_f32_16x16x32_bf16(a, b, h, 0, 0, 0);
  }
  if (r16 < 10) {
    float bv = b3[r16];
    int rowb = w * 16 + (lane >> 4) * 4;
#pragma unroll
    for (int q = 0; q < 4; q++) {
      int node = node0 + rowb + q;
      if (node < n) out[(size_t)node * 10 + r16] = h[q] + bv;
    }
  }
}

extern "C" void kernel_launch(void* const* d_in, const int* in_sizes, int n_in,
                              void* d_out, int out_size, void* d_ws, size_t ws_size,
                              hipStream_t stream) {
  const float* x    = (const float*)d_in[0];
  const int*   esrc = (const int*)d_in[1];
  const int*   edst = (const int*)d_in[2];
  const float* W1   = (const float*)d_in[3];
  const float* b1   = (const float*)d_in[4];
  const float* W2   = (const float*)d_in[5];
  const float* b2   = (const float*)d_in[6];
  const float* W3   = (const float*)d_in[7];
  const float* b3   = (const float*)d_in[8];
  float* out = (float*)d_out;

  const int N = in_sizes[0] / DF;   // 100000
  const int E = in_sizes[1];        // 1600000

  const int nbuck   = (N + 255) >> 8;            // 391
  const int nblocks = (E + EPB - 1) / EPB;       // 782
  const int M = nbuck * nblocks;                 // ~306K

  // workspace layout
  char* ws = (char*)d_ws;
  int*  rowptr = (int*)ws;               // N+1
  int*  csr    = rowptr + (N + 1);       // E
  int*  histG  = csr + E;                // M
  int*  histE  = histG + M;              // M
  int*  bsums2 = histE + M;              // 1024
  uint* eb     = (uint*)(bsums2 + 1024); // E
  size_t off = (size_t)((char*)(eb + E) - ws);
  off = (off + 255) & ~(size_t)255;
  ushort* xb  = (ushort*)(ws + off);     off += (size_t)N * DF * 2; off = (off + 255) & ~(size_t)255;
  ushort* Wt1 = (ushort*)(ws + off);     off += (size_t)DF * DF * 2;
  ushort* Wt2 = (ushort*)(ws + off);     off += (size_t)DF * DF * 2;
  ushort* W3t = (ushort*)(ws + off);     off += (size_t)16 * DF * 2; off = (off + 255) & ~(size_t)255;
  ushort* bufB = (ushort*)(ws + off);

  // prep (convert + 3 transposes in one launch)
  int n4 = N * DF / 4;
  int prep_total = n4 + 2 * DF * DF + 16 * DF;
  prep_kernel<<<(prep_total + 255) / 256, 256, 0, stream>>>(x, xb, W1, Wt1, W2, Wt2, W3, W3t, n4);

  // CSR build
  size_t lds_b = (size_t)nbuck * sizeof(int);
  bucket_hist_kernel<<<nblocks, 256, lds_b, stream>>>(edst, histG, E, nbuck, nblocks);
  int nb_m = (M + 1023) / 1024;
  scan1_kernel<<<nb_m, 256, 0, stream>>>(histG, histE, bsums2, M);
  scan2_kernel<<<1, 1024, 0, stream>>>(bsums2, nb_m);
  bucket_scatter_kernel<<<nblocks, 256, lds_b, stream>>>(esrc, edst, histE, bsums2, eb, E, nbuck, nblocks);
  bucket_sort_kernel<<<nbuck, 256, 0, stream>>>(eb, histE, bsums2, rowptr, csr, N, E, nbuck, nblocks);

  int blocks = (N + 63) / 64;
  fused_layer_kernel<<<blocks, 256, 0, stream>>>(xb, rowptr, csr, Wt1, b1, bufB, N);
  fused_layer_head_kernel<<<blocks, 256, 0, stream>>>(bufB, rowptr, csr, Wt2, b2, W3t, b3, out, N);
}

// Round 6
// 240.622 us; speedup vs baseline: 1.4459x; 1.4459x over previous
//
#include <hip/hip_runtime.h>

#define DF 128
#define AST 136   // padded LDS row stride (bf16 elems)
#define EPB 2048  // edges per block in bucket passes

typedef float f32x4 __attribute__((ext_vector_type(4)));
typedef short bf16x8 __attribute__((ext_vector_type(8)));

__device__ __forceinline__ ushort f2bf(float f) {
  union { float f; uint u; } c; c.f = f;
  uint u = c.u;
  uint r = (u + 0x7fffu + ((u >> 16) & 1u)) >> 16;   // RNE
  return (ushort)r;
}
__device__ __forceinline__ float bf_lo(uint v) { union { uint u; float f; } c; c.u = v << 16; return c.f; }
__device__ __forceinline__ float bf_hi(uint v) { union { uint u; float f; } c; c.u = v & 0xffff0000u; return c.f; }

__device__ __forceinline__ void addv8(float* acc, uint4 v) {
  acc[0] += bf_lo(v.x); acc[1] += bf_hi(v.x);
  acc[2] += bf_lo(v.y); acc[3] += bf_hi(v.y);
  acc[4] += bf_lo(v.z); acc[5] += bf_hi(v.z);
  acc[6] += bf_lo(v.w); acc[7] += bf_hi(v.w);
}

// ---------------- prep: convert x to bf16, transpose W1/W2/W3 to bf16 ----------------
__global__ void prep_kernel(const float* __restrict__ x, ushort* __restrict__ xb,
                            const float* __restrict__ W1, ushort* __restrict__ Wt1,
                            const float* __restrict__ W2, ushort* __restrict__ Wt2,
                            const float* __restrict__ W3, ushort* __restrict__ W3t, int n4) {
  int i = blockIdx.x * 256 + threadIdx.x;
  if (i < n4) {
    float4 v = ((const float4*)x)[i];
    ushort4 o; o.x = f2bf(v.x); o.y = f2bf(v.y); o.z = f2bf(v.z); o.w = f2bf(v.w);
    ((ushort4*)xb)[i] = o;
    return;
  }
  int j = i - n4;
  if (j < DF * DF) {
    int nr = j >> 7, k = j & 127;
    Wt1[j] = f2bf(W1[(size_t)k * DF + nr]);
    return;
  }
  j -= DF * DF;
  if (j < DF * DF) {
    int nr = j >> 7, k = j & 127;
    Wt2[j] = f2bf(W2[(size_t)k * DF + nr]);
    return;
  }
  j -= DF * DF;
  if (j < 16 * DF) {
    int nr = j >> 7, k = j & 127;
    W3t[j] = (nr < 10) ? f2bf(W3[(size_t)k * 10 + nr]) : (ushort)0;
  }
}

// ---------------- CSR build: two-level counting sort (bucket = dst >> 8) ----------------

__global__ void bucket_hist_kernel(const int* __restrict__ dst, int* __restrict__ histG,
                                   int E, int nbuck, int nblocks) {
  extern __shared__ int lh[];
  int tid = threadIdx.x, blk = blockIdx.x;
  for (int i = tid; i < nbuck; i += 256) lh[i] = 0;
  __syncthreads();
  int base = blk * EPB;
#pragma unroll
  for (int it = 0; it < EPB / 256; ++it) {
    int e = base + it * 256 + tid;
    if (e < E) atomicAdd(&lh[dst[e] >> 8], 1);
  }
  __syncthreads();
  for (int i = tid; i < nbuck; i += 256) histG[(size_t)i * nblocks + blk] = lh[i];
}

// generic scan, 1024 elems/block
__global__ void scan1_kernel(const int* __restrict__ cnt, int* __restrict__ excl,
                             int* __restrict__ bsums, int n) {
  __shared__ int wsum[4];
  int t = threadIdx.x;
  int base = blockIdx.x * 1024 + t * 4;
  int v[4]; int s = 0;
#pragma unroll
  for (int i = 0; i < 4; i++) { int d = (base + i < n) ? cnt[base + i] : 0; v[i] = s; s += d; }
  int lane = t & 63, w = t >> 6;
  int sc = s;
#pragma unroll
  for (int off = 1; off < 64; off <<= 1) { int o = __shfl_up(sc, off); if (lane >= off) sc += o; }
  if (lane == 63) wsum[w] = sc;
  __syncthreads();
  int woff = 0;
  for (int i = 0; i < w; i++) woff += wsum[i];
  int toff = woff + (sc - s);
#pragma unroll
  for (int i = 0; i < 4; i++) if (base + i < n) excl[base + i] = toff + v[i];
  if (t == 255) bsums[blockIdx.x] = woff + sc;
}

// single-block exclusive scan for up to 1024 block-sums (wave-parallel)
__global__ void scan2_kernel(int* bsums, int nb) {
  __shared__ int wsum[16];
  int t = threadIdx.x;
  int v = (t < nb) ? bsums[t] : 0;
  int lane = t & 63, w = t >> 6;
  int sc = v;
#pragma unroll
  for (int off = 1; off < 64; off <<= 1) { int o = __shfl_up(sc, off); if (lane >= off) sc += o; }
  if (lane == 63) wsum[w] = sc;
  __syncthreads();
  int woff = 0;
  for (int i = 0; i < w; i++) woff += wsum[i];
  if (t < nb) bsums[t] = woff + sc - v;
}

// scatter edges into bucket-contiguous packed array: src | (dst&255)<<24
__global__ void bucket_scatter_kernel(const int* __restrict__ src, const int* __restrict__ dst,
                                      const int* __restrict__ histE, const int* __restrict__ bsums,
                                      uint* __restrict__ eb, int E, int nbuck, int nblocks) {
  extern __shared__ int lc[];
  int tid = threadIdx.x, blk = blockIdx.x;
  for (int i = tid; i < nbuck; i += 256) {
    int idx = i * nblocks + blk;
    lc[i] = histE[idx] + bsums[idx >> 10];
  }
  __syncthreads();
  int base = blk * EPB;
#pragma unroll
  for (int it = 0; it < EPB / 256; ++it) {
    int e = base + it * 256 + tid;
    if (e < E) {
      int d = dst[e];
      int pos = atomicAdd(&lc[d >> 8], 1);
      eb[pos] = (uint)src[e] | ((uint)(d & 255) << 24);
    }
  }
}

// one block per bucket: counting sort over 256 nodes, emit rowptr + csr
__global__ void bucket_sort_kernel(const uint* __restrict__ eb,
                                   const int* __restrict__ histE, const int* __restrict__ bsums,
                                   int* __restrict__ rowptr, int* __restrict__ csr,
                                   int N, int E, int nbuck, int nblocks) {
  __shared__ int cnt[256];
  __shared__ int cursor[256];
  __shared__ int wsum[4];
  int tid = threadIdx.x, b = blockIdx.x;
  int idx = b * nblocks;
  int beg = histE[idx] + bsums[idx >> 10];
  int end = E;
  if (b + 1 < nbuck) { int i2 = (b + 1) * nblocks; end = histE[i2] + bsums[i2 >> 10]; }
  cnt[tid] = 0;
  __syncthreads();
  for (int e = beg + tid; e < end; e += 256)
    atomicAdd(&cnt[eb[e] >> 24], 1);
  __syncthreads();
  int v = cnt[tid];
  int lane = tid & 63, w = tid >> 6;
  int sc = v;
#pragma unroll
  for (int off = 1; off < 64; off <<= 1) { int o = __shfl_up(sc, off); if (lane >= off) sc += o; }
  if (lane == 63) wsum[w] = sc;
  __syncthreads();
  int woff = 0;
  for (int i = 0; i < w; i++) woff += wsum[i];
  int excl = woff + sc - v;
  int node = (b << 8) + tid;
  if (node <= N) rowptr[node] = beg + excl;
  cursor[tid] = beg + excl;
  __syncthreads();
  for (int e = beg + tid; e < end; e += 256) {
    uint vv = eb[e];
    int pos = atomicAdd(&cursor[vv >> 24], 1);
    csr[pos] = (int)(vv & 0x00FFFFFFu);
  }
}

// ---------------- scatter-mean as CSR gather: one wave per node ----------------
// 16 lanes x 16B per row -> 4 edges per load instruction; shfl_xor(16,32) reduce.
__global__ void aggregate_kernel(const ushort* __restrict__ xb, const int* __restrict__ rowptr,
                                 const int* __restrict__ csr, ushort* __restrict__ out, int n) {
  int gw = (blockIdx.x * blockDim.x + threadIdx.x) >> 6;
  int lane = threadIdx.x & 63;
  if (gw >= n) return;
  int beg = rowptr[gw], end = rowptr[gw + 1];
  const uint4* x4 = (const uint4*)xb;     // 8 bf16 per 16B
  int g = lane >> 4, c = lane & 15;
  float acc[8];
#pragma unroll
  for (int i = 0; i < 8; i++) acc[i] = 0.f;

  int e = beg;
#pragma unroll 2
  for (; e + 8 <= end; e += 8) {
    int i0 = csr[e + g];
    int i1 = csr[e + 4 + g];
    uint4 v0 = x4[(size_t)i0 * 16 + c];
    uint4 v1 = x4[(size_t)i1 * 16 + c];
    addv8(acc, v0);
    addv8(acc, v1);
  }
  for (; e < end; e += 4) {
    int edge = e + g;
    int idx = csr[edge < end ? edge : end - 1];
    uint4 v = x4[(size_t)idx * 16 + c];
    if (edge < end) addv8(acc, v);
  }

#pragma unroll
  for (int i = 0; i < 8; i++) {
    acc[i] += __shfl_xor(acc[i], 16);
    acc[i] += __shfl_xor(acc[i], 32);
  }

  int deg = end - beg;
  if (lane < 16) {
    uint4 r;
    if (deg > 0) {
      float inv = 1.0f / (float)deg;
      r.x = (uint)f2bf(acc[0] * inv) | ((uint)f2bf(acc[1] * inv) << 16);
      r.y = (uint)f2bf(acc[2] * inv) | ((uint)f2bf(acc[3] * inv) << 16);
      r.z = (uint)f2bf(acc[4] * inv) | ((uint)f2bf(acc[5] * inv) << 16);
      r.w = (uint)f2bf(acc[6] * inv) | ((uint)f2bf(acc[7] * inv) << 16);
    } else {
      r = x4[(size_t)gw * 16 + c];
    }
    ((uint4*)out)[(size_t)gw * 16 + c] = r;
  }
}

// ---------------- GEMM [n x 128] @ W[128 x 128] + bias + tanh, bf16 MFMA ----------------
__global__ __launch_bounds__(256) void gemm_tanh_mfma(
    const ushort* __restrict__ A, const ushort* __restrict__ Wt,
    const float* __restrict__ bias, ushort* __restrict__ out, int n) {
  __shared__ ushort As[64 * AST];
  __shared__ ushort Ws[128 * AST];
  int tid = threadIdx.x;
  int node0 = blockIdx.x * 64;

  for (int i = tid; i < 64 * 16; i += 256) {
    int r = i >> 4, c = i & 15;
    int node = node0 + r; if (node >= n) node = n - 1;
    uint4 v = ((const uint4*)(A + (size_t)node * DF))[c];
    *(uint4*)&As[r * AST + c * 8] = v;
  }
  for (int i = tid; i < 128 * 16; i += 256) {
    int r = i >> 4, c = i & 15;
    uint4 v = ((const uint4*)(Wt + r * DF))[c];
    *(uint4*)&Ws[r * AST + c * 8] = v;
  }
  __syncthreads();

  int lane = tid & 63, w = tid >> 6;
  int wr = (w >> 1) * 32;
  int wc = (w & 1) * 64;
  int r16 = lane & 15, g8 = (lane >> 4) * 8;

  f32x4 acc[2][4];
#pragma unroll
  for (int i = 0; i < 2; i++)
#pragma unroll
    for (int j = 0; j < 4; j++) acc[i][j] = (f32x4){0.f, 0.f, 0.f, 0.f};

#pragma unroll
  for (int ks = 0; ks < 4; ++ks) {
    int k0 = ks * 32 + g8;
    bf16x8 a0 = *(const bf16x8*)&As[(wr + r16) * AST + k0];
    bf16x8 a1 = *(const bf16x8*)&As[(wr + 16 + r16) * AST + k0];
#pragma unroll
    for (int j = 0; j < 4; j++) {
      bf16x8 b = *(const bf16x8*)&Ws[(wc + j * 16 + r16) * AST + k0];
      acc[0][j] = __builtin_amdgcn_mfma_f32_16x16x32_bf16(a0, b, acc[0][j], 0, 0, 0);
      acc[1][j] = __builtin_amdgcn_mfma_f32_16x16x32_bf16(a1, b, acc[1][j], 0, 0, 0);
    }
  }

#pragma unroll
  for (int mi = 0; mi < 2; mi++) {
#pragma unroll
    for (int j = 0; j < 4; j++) {
      int col = wc + j * 16 + r16;
      float bv = bias[col];
      int rowb = wr + mi * 16 + (lane >> 4) * 4;
#pragma unroll
      for (int q = 0; q < 4; q++) {
        int node = node0 + rowb + q;
        if (node < n) {
          float vv = tanhf(acc[mi][j][q] + bv);
          out[(size_t)node * DF + col] = f2bf(vv);
        }
      }
    }
  }
}

// ---------------- head: [n x 128] @ W3[128 x 10] + bias, bf16 MFMA, f32 out ----------------
__global__ __launch_bounds__(256) void head_mfma(
    const ushort* __restrict__ A, const ushort* __restrict__ W3t,
    const float* __restrict__ bias, float* __restrict__ out, int n) {
  __shared__ ushort As[128 * AST];
  __shared__ ushort Ws[16 * AST];
  int tid = threadIdx.x;
  int node0 = blockIdx.x * 128;

  for (int i = tid; i < 128 * 16; i += 256) {
    int r = i >> 4, c = i & 15;
    int node = node0 + r; if (node >= n) node = n - 1;
    uint4 v = ((const uint4*)(A + (size_t)node * DF))[c];
    *(uint4*)&As[r * AST + c * 8] = v;
  }
  if (tid < 16 * 16) {
    int r = tid >> 4, c = tid & 15;
    uint4 v = ((const uint4*)(W3t + r * DF))[c];
    *(uint4*)&Ws[r * AST + c * 8] = v;
  }
  __syncthreads();

  int lane = tid & 63, w = tid >> 6;
  int r16 = lane & 15, g8 = (lane >> 4) * 8;
  f32x4 acc[2];
  acc[0] = (f32x4){0.f, 0.f, 0.f, 0.f};
  acc[1] = (f32x4){0.f, 0.f, 0.f, 0.f};

#pragma unroll
  for (int ks = 0; ks < 4; ++ks) {
    int k0 = ks * 32 + g8;
    bf16x8 b  = *(const bf16x8*)&Ws[r16 * AST + k0];
    bf16x8 a0 = *(const bf16x8*)&As[(w * 32 + r16) * AST + k0];
    bf16x8 a1 = *(const bf16x8*)&As[(w * 32 + 16 + r16) * AST + k0];
    acc[0] = __builtin_amdgcn_mfma_f32_16x16x32_bf16(a0, b, acc[0], 0, 0, 0);
    acc[1] = __builtin_amdgcn_mfma_f32_16x16x32_bf16(a1, b, acc[1], 0, 0, 0);
  }

  int col = r16;
  if (col < 10) {
    float bv = bias[col];
#pragma unroll
    for (int mi = 0; mi < 2; mi++) {
      int rowb = w * 32 + mi * 16 + (lane >> 4) * 4;
#pragma unroll
      for (int q = 0; q < 4; q++) {
        int node = node0 + rowb + q;
        if (node < n) out[(size_t)node * 10 + col] = acc[mi][q] + bv;
      }
    }
  }
}

extern "C" void kernel_launch(void* const* d_in, const int* in_sizes, int n_in,
                              void* d_out, int out_size, void* d_ws, size_t ws_size,
                              hipStream_t stream) {
  const float* x    = (const float*)d_in[0];
  const int*   esrc = (const int*)d_in[1];
  const int*   edst = (const int*)d_in[2];
  const float* W1   = (const float*)d_in[3];
  const float* b1   = (const float*)d_in[4];
  const float* W2   = (const float*)d_in[5];
  const float* b2   = (const float*)d_in[6];
  const float* W3   = (const float*)d_in[7];
  const float* b3   = (const float*)d_in[8];
  float* out = (float*)d_out;

  const int N = in_sizes[0] / DF;   // 100000
  const int E = in_sizes[1];        // 1600000

  const int nbuck   = (N + 255) >> 8;            // 391
  const int nblocks = (E + EPB - 1) / EPB;       // 782
  const int M = nbuck * nblocks;                 // ~306K

  // workspace layout
  char* ws = (char*)d_ws;
  int*  rowptr = (int*)ws;               // N+1
  int*  csr    = rowptr + (N + 1);       // E
  int*  histG  = csr + E;                // M
  int*  histE  = histG + M;              // M
  int*  bsums2 = histE + M;              // 1024
  uint* eb     = (uint*)(bsums2 + 1024); // E
  size_t off = (size_t)((char*)(eb + E) - ws);
  off = (off + 255) & ~(size_t)255;
  ushort* xb  = (ushort*)(ws + off);     off += (size_t)N * DF * 2; off = (off + 255) & ~(size_t)255;
  ushort* Wt1 = (ushort*)(ws + off);     off += (size_t)DF * DF * 2;
  ushort* Wt2 = (ushort*)(ws + off);     off += (size_t)DF * DF * 2;
  ushort* W3t = (ushort*)(ws + off);     off += (size_t)16 * DF * 2; off = (off + 255) & ~(size_t)255;
  ushort* bufA = (ushort*)(ws + off);    off += (size_t)N * DF * 2; off = (off + 255) & ~(size_t)255;
  ushort* bufB = (ushort*)(ws + off);

  // prep (convert + 3 transposes in one launch)
  int n4 = N * DF / 4;
  int prep_total = n4 + 2 * DF * DF + 16 * DF;
  prep_kernel<<<(prep_total + 255) / 256, 256, 0, stream>>>(x, xb, W1, Wt1, W2, Wt2, W3, W3t, n4);

  // CSR build
  size_t lds_b = (size_t)nbuck * sizeof(int);
  bucket_hist_kernel<<<nblocks, 256, lds_b, stream>>>(edst, histG, E, nbuck, nblocks);
  int nb_m = (M + 1023) / 1024;
  scan1_kernel<<<nb_m, 256, 0, stream>>>(histG, histE, bsums2, M);
  scan2_kernel<<<1, 1024, 0, stream>>>(bsums2, nb_m);
  bucket_scatter_kernel<<<nblocks, 256, lds_b, stream>>>(esrc, edst, histE, bsums2, eb, E, nbuck, nblocks);
  bucket_sort_kernel<<<nbuck, 256, 0, stream>>>(eb, histE, bsums2, rowptr, csr, N, E, nbuck, nblocks);

  int agg_blocks = (N * 64 + 255) / 256;   // one wave per node
  int gemm_blocks = (N + 63) / 64;
  int head_blocks = (N + 127) / 128;

  // layer 1
  aggregate_kernel<<<agg_blocks, 256, 0, stream>>>(xb, rowptr, csr, bufA, N);
  gemm_tanh_mfma<<<gemm_blocks, 256, 0, stream>>>(bufA, Wt1, b1, bufB, N);
  // layer 2
  aggregate_kernel<<<agg_blocks, 256, 0, stream>>>(bufB, rowptr, csr, bufA, N);
  gemm_tanh_mfma<<<gemm_blocks, 256, 0, stream>>>(bufA, Wt2, b2, bufB, N);
  // head
  head_mfma<<<head_blocks, 256, 0, stream>>>(bufB, W3t, b3, out, N);
}

// Round 7
// 226.095 us; speedup vs baseline: 1.5388x; 1.0643x over previous
//
#include <hip/hip_runtime.h>

#define DF 128
#define AST 136   // padded LDS row stride (bf16 elems)
#define EPB 2048  // edges per block in bucket passes

typedef float f32x4 __attribute__((ext_vector_type(4)));
typedef short bf16x8 __attribute__((ext_vector_type(8)));

__device__ __forceinline__ ushort f2bf(float f) {
  union { float f; uint u; } c; c.f = f;
  uint u = c.u;
  uint r = (u + 0x7fffu + ((u >> 16) & 1u)) >> 16;   // RNE
  return (ushort)r;
}
__device__ __forceinline__ float bf_lo(uint v) { union { uint u; float f; } c; c.u = v << 16; return c.f; }
__device__ __forceinline__ float bf_hi(uint v) { union { uint u; float f; } c; c.u = v & 0xffff0000u; return c.f; }

__device__ __forceinline__ void addv8(float* acc, uint4 v) {
  acc[0] += bf_lo(v.x); acc[1] += bf_hi(v.x);
  acc[2] += bf_lo(v.y); acc[3] += bf_hi(v.y);
  acc[4] += bf_lo(v.z); acc[5] += bf_hi(v.z);
  acc[6] += bf_lo(v.w); acc[7] += bf_hi(v.w);
}

// ---------------- prep: convert x->bf16, transpose W1/W2/W3, zero dummy rows ----------------
__global__ void prep_kernel(const float* __restrict__ x, ushort* __restrict__ xb,
                            const float* __restrict__ W1, ushort* __restrict__ Wt1,
                            const float* __restrict__ W2, ushort* __restrict__ Wt2,
                            const float* __restrict__ W3, ushort* __restrict__ W3t,
                            ushort* __restrict__ xbN, ushort* __restrict__ bufBN, int n4) {
  int i = blockIdx.x * 256 + threadIdx.x;
  if (i < n4) {
    float4 v = ((const float4*)x)[i];
    ushort4 o; o.x = f2bf(v.x); o.y = f2bf(v.y); o.z = f2bf(v.z); o.w = f2bf(v.w);
    ((ushort4*)xb)[i] = o;
    return;
  }
  int j = i - n4;
  if (j < DF * DF) {
    int nr = j >> 7, k = j & 127;
    Wt1[j] = f2bf(W1[(size_t)k * DF + nr]);
    return;
  }
  j -= DF * DF;
  if (j < DF * DF) {
    int nr = j >> 7, k = j & 127;
    Wt2[j] = f2bf(W2[(size_t)k * DF + nr]);
    return;
  }
  j -= DF * DF;
  if (j < 16 * DF) {
    int nr = j >> 7, k = j & 127;
    W3t[j] = (nr < 10) ? f2bf(W3[(size_t)k * 10 + nr]) : (ushort)0;
    return;
  }
  j -= 16 * DF;
  if (j < 16) { ((uint4*)xbN)[j] = (uint4){0, 0, 0, 0}; return; }
  j -= 16;
  if (j < 16) { ((uint4*)bufBN)[j] = (uint4){0, 0, 0, 0}; }
}

// ---------------- CSR build: two-level counting sort (bucket = dst >> 8) ----------------

__global__ void bucket_hist_kernel(const int* __restrict__ dst, int* __restrict__ histG,
                                   int E, int nbuck, int nblocks) {
  extern __shared__ int lh[];
  int tid = threadIdx.x, blk = blockIdx.x;
  for (int i = tid; i < nbuck; i += 256) lh[i] = 0;
  __syncthreads();
  int base = blk * EPB;
#pragma unroll
  for (int it = 0; it < EPB / 256; ++it) {
    int e = base + it * 256 + tid;
    if (e < E) atomicAdd(&lh[dst[e] >> 8], 1);
  }
  __syncthreads();
  for (int i = tid; i < nbuck; i += 256) histG[(size_t)i * nblocks + blk] = lh[i];
}

__global__ void scan1_kernel(const int* __restrict__ cnt, int* __restrict__ excl,
                             int* __restrict__ bsums, int n) {
  __shared__ int wsum[4];
  int t = threadIdx.x;
  int base = blockIdx.x * 1024 + t * 4;
  int v[4]; int s = 0;
#pragma unroll
  for (int i = 0; i < 4; i++) { int d = (base + i < n) ? cnt[base + i] : 0; v[i] = s; s += d; }
  int lane = t & 63, w = t >> 6;
  int sc = s;
#pragma unroll
  for (int off = 1; off < 64; off <<= 1) { int o = __shfl_up(sc, off); if (lane >= off) sc += o; }
  if (lane == 63) wsum[w] = sc;
  __syncthreads();
  int woff = 0;
  for (int i = 0; i < w; i++) woff += wsum[i];
  int toff = woff + (sc - s);
#pragma unroll
  for (int i = 0; i < 4; i++) if (base + i < n) excl[base + i] = toff + v[i];
  if (t == 255) bsums[blockIdx.x] = woff + sc;
}

__global__ void scan2_kernel(int* bsums, int nb) {
  __shared__ int wsum[16];
  int t = threadIdx.x;
  int v = (t < nb) ? bsums[t] : 0;
  int lane = t & 63, w = t >> 6;
  int sc = v;
#pragma unroll
  for (int off = 1; off < 64; off <<= 1) { int o = __shfl_up(sc, off); if (lane >= off) sc += o; }
  if (lane == 63) wsum[w] = sc;
  __syncthreads();
  int woff = 0;
  for (int i = 0; i < w; i++) woff += wsum[i];
  if (t < nb) bsums[t] = woff + sc - v;
}

__global__ void bucket_scatter_kernel(const int* __restrict__ src, const int* __restrict__ dst,
                                      const int* __restrict__ histE, const int* __restrict__ bsums,
                                      uint* __restrict__ eb, int E, int nbuck, int nblocks) {
  extern __shared__ int lc[];
  int tid = threadIdx.x, blk = blockIdx.x;
  for (int i = tid; i < nbuck; i += 256) {
    int idx = i * nblocks + blk;
    lc[i] = histE[idx] + bsums[idx >> 10];
  }
  __syncthreads();
  int base = blk * EPB;
#pragma unroll
  for (int it = 0; it < EPB / 256; ++it) {
    int e = base + it * 256 + tid;
    if (e < E) {
      int d = dst[e];
      int pos = atomicAdd(&lc[d >> 8], 1);
      eb[pos] = (uint)src[e] | ((uint)(d & 255) << 24);
    }
  }
}

__global__ void bucket_sort_kernel(const uint* __restrict__ eb,
                                   const int* __restrict__ histE, const int* __restrict__ bsums,
                                   int* __restrict__ rowptr, int* __restrict__ csr,
                                   int N, int E, int nbuck, int nblocks) {
  __shared__ int cnt[256];
  __shared__ int cursor[256];
  __shared__ int wsum[4];
  int tid = threadIdx.x, b = blockIdx.x;
  int idx = b * nblocks;
  int beg = histE[idx] + bsums[idx >> 10];
  int end = E;
  if (b + 1 < nbuck) { int i2 = (b + 1) * nblocks; end = histE[i2] + bsums[i2 >> 10]; }
  cnt[tid] = 0;
  __syncthreads();
  for (int e = beg + tid; e < end; e += 256)
    atomicAdd(&cnt[eb[e] >> 24], 1);
  __syncthreads();
  int v = cnt[tid];
  int lane = tid & 63, w = tid >> 6;
  int sc = v;
#pragma unroll
  for (int off = 1; off < 64; off <<= 1) { int o = __shfl_up(sc, off); if (lane >= off) sc += o; }
  if (lane == 63) wsum[w] = sc;
  __syncthreads();
  int woff = 0;
  for (int i = 0; i < w; i++) woff += wsum[i];
  int excl = woff + sc - v;
  int node = (b << 8) + tid;
  if (node <= N) rowptr[node] = beg + excl;
  cursor[tid] = beg + excl;
  __syncthreads();
  for (int e = beg + tid; e < end; e += 256) {
    uint vv = eb[e];
    int pos = atomicAdd(&cursor[vv >> 24], 1);
    csr[pos] = (int)(vv & 0x00FFFFFFu);
  }
}

// ---------------- scatter-mean as CSR gather: one wave per node ----------------
// 16 lanes x 16B per row, 16 edges (4 KB) in flight per iter; OOR edges clamp
// to all-zero row n (L1-resident). 32-bit byte offsets -> saddr loads.
__global__ __launch_bounds__(256) void aggregate_kernel(
    const ushort* __restrict__ xb, const int* __restrict__ rowptr,
    const int* __restrict__ csr, ushort* __restrict__ out, int n) {
  int gw = (blockIdx.x * 256 + threadIdx.x) >> 6;
  int lane = threadIdx.x & 63;
  if (gw >= n) return;
  int beg = rowptr[gw], end = rowptr[gw + 1];
  int g = lane >> 4;
  uint coff = (uint)(lane & 15) * 16u;   // byte offset within 256B row
  const char* xbase = (const char*)xb;
  float acc[8];
#pragma unroll
  for (int i = 0; i < 8; i++) acc[i] = 0.f;

#pragma unroll 1
  for (int e = beg; e < end; e += 16) {
    int e0 = e + g, e1 = e + 4 + g, e2 = e + 8 + g, e3 = e + 12 + g;
    int last = end - 1;
    int i0 = csr[e0 < end ? e0 : last];
    int i1 = csr[e1 < end ? e1 : last];
    int i2 = csr[e2 < end ? e2 : last];
    int i3 = csr[e3 < end ? e3 : last];
    uint r0 = (e0 < end) ? (uint)i0 : (uint)n;
    uint r1 = (e1 < end) ? (uint)i1 : (uint)n;
    uint r2 = (e2 < end) ? (uint)i2 : (uint)n;
    uint r3 = (e3 < end) ? (uint)i3 : (uint)n;
    uint4 v0 = *(const uint4*)(xbase + (r0 * 256u + coff));
    uint4 v1 = *(const uint4*)(xbase + (r1 * 256u + coff));
    uint4 v2 = *(const uint4*)(xbase + (r2 * 256u + coff));
    uint4 v3 = *(const uint4*)(xbase + (r3 * 256u + coff));
    addv8(acc, v0);
    addv8(acc, v1);
    addv8(acc, v2);
    addv8(acc, v3);
  }

#pragma unroll
  for (int i = 0; i < 8; i++) {
    acc[i] += __shfl_xor(acc[i], 16);
    acc[i] += __shfl_xor(acc[i], 32);
  }

  int deg = end - beg;
  if (lane < 16) {
    uint4 r;
    if (deg > 0) {
      float inv = 1.0f / (float)deg;
      r.x = (uint)f2bf(acc[0] * inv) | ((uint)f2bf(acc[1] * inv) << 16);
      r.y = (uint)f2bf(acc[2] * inv) | ((uint)f2bf(acc[3] * inv) << 16);
      r.z = (uint)f2bf(acc[4] * inv) | ((uint)f2bf(acc[5] * inv) << 16);
      r.w = (uint)f2bf(acc[6] * inv) | ((uint)f2bf(acc[7] * inv) << 16);
    } else {
      r = *(const uint4*)(xbase + ((uint)gw * 256u + coff));
    }
    *(uint4*)((char*)out + ((uint)gw * 256u + coff)) = r;
  }
}

// ---------------- GEMM1 [n x 128] @ W[128 x 128] + bias + tanh, bf16 MFMA ----------------
__global__ __launch_bounds__(256) void gemm_tanh_mfma(
    const ushort* __restrict__ A, const ushort* __restrict__ Wt,
    const float* __restrict__ bias, ushort* __restrict__ out, int n) {
  __shared__ ushort As[64 * AST];
  __shared__ ushort Ws[128 * AST];
  int tid = threadIdx.x;
  int node0 = blockIdx.x * 64;

  for (int i = tid; i < 64 * 16; i += 256) {
    int r = i >> 4, c = i & 15;
    int node = node0 + r; if (node >= n) node = n - 1;
    uint4 v = ((const uint4*)(A + (size_t)node * DF))[c];
    *(uint4*)&As[r * AST + c * 8] = v;
  }
  for (int i = tid; i < 128 * 16; i += 256) {
    int r = i >> 4, c = i & 15;
    uint4 v = ((const uint4*)(Wt + r * DF))[c];
    *(uint4*)&Ws[r * AST + c * 8] = v;
  }
  __syncthreads();

  int lane = tid & 63, w = tid >> 6;
  int wr = (w >> 1) * 32;
  int wc = (w & 1) * 64;
  int r16 = lane & 15, g8 = (lane >> 4) * 8;

  f32x4 acc[2][4];
#pragma unroll
  for (int i = 0; i < 2; i++)
#pragma unroll
    for (int j = 0; j < 4; j++) acc[i][j] = (f32x4){0.f, 0.f, 0.f, 0.f};

#pragma unroll
  for (int ks = 0; ks < 4; ++ks) {
    int k0 = ks * 32 + g8;
    bf16x8 a0 = *(const bf16x8*)&As[(wr + r16) * AST + k0];
    bf16x8 a1 = *(const bf16x8*)&As[(wr + 16 + r16) * AST + k0];
#pragma unroll
    for (int j = 0; j < 4; j++) {
      bf16x8 b = *(const bf16x8*)&Ws[(wc + j * 16 + r16) * AST + k0];
      acc[0][j] = __builtin_amdgcn_mfma_f32_16x16x32_bf16(a0, b, acc[0][j], 0, 0, 0);
      acc[1][j] = __builtin_amdgcn_mfma_f32_16x16x32_bf16(a1, b, acc[1][j], 0, 0, 0);
    }
  }

#pragma unroll
  for (int mi = 0; mi < 2; mi++) {
#pragma unroll
    for (int j = 0; j < 4; j++) {
      int col = wc + j * 16 + r16;
      float bv = bias[col];
      int rowb = wr + mi * 16 + (lane >> 4) * 4;
#pragma unroll
      for (int q = 0; q < 4; q++) {
        int node = node0 + rowb + q;
        if (node < n) {
          float vv = tanhf(acc[mi][j][q] + bv);
          out[(size_t)node * DF + col] = f2bf(vv);
        }
      }
    }
  }
}

// ---------------- GEMM2 + head fused: h2 = tanh(A@W2+b2) -> LDS -> logits = h2@W3+b3
__global__ __launch_bounds__(256) void gemm2_head_mfma(
    const ushort* __restrict__ A, const ushort* __restrict__ Wt,
    const float* __restrict__ bias, const ushort* __restrict__ W3t,
    const float* __restrict__ b3, float* __restrict__ out, int n) {
  __shared__ ushort As[64 * AST];
  __shared__ ushort Ws[128 * AST];
  __shared__ ushort W3s[16 * AST];
  int tid = threadIdx.x;
  int node0 = blockIdx.x * 64;

  for (int i = tid; i < 64 * 16; i += 256) {
    int r = i >> 4, c = i & 15;
    int node = node0 + r; if (node >= n) node = n - 1;
    uint4 v = ((const uint4*)(A + (size_t)node * DF))[c];
    *(uint4*)&As[r * AST + c * 8] = v;
  }
  for (int i = tid; i < 128 * 16; i += 256) {
    int r = i >> 4, c = i & 15;
    uint4 v = ((const uint4*)(Wt + r * DF))[c];
    *(uint4*)&Ws[r * AST + c * 8] = v;
  }
  {
    int r = tid >> 4, c = tid & 15;
    uint4 v = ((const uint4*)(W3t + r * DF))[c];
    *(uint4*)&W3s[r * AST + c * 8] = v;
  }
  __syncthreads();

  int lane = tid & 63, w = tid >> 6;
  int wr = (w >> 1) * 32, wc = (w & 1) * 64;
  int r16 = lane & 15, g8 = (lane >> 4) * 8;

  f32x4 acc[2][4];
#pragma unroll
  for (int i = 0; i < 2; i++)
#pragma unroll
    for (int j = 0; j < 4; j++) acc[i][j] = (f32x4){0.f, 0.f, 0.f, 0.f};

#pragma unroll
  for (int ks = 0; ks < 4; ++ks) {
    int k0 = ks * 32 + g8;
    bf16x8 a0 = *(const bf16x8*)&As[(wr + r16) * AST + k0];
    bf16x8 a1 = *(const bf16x8*)&As[(wr + 16 + r16) * AST + k0];
#pragma unroll
    for (int j = 0; j < 4; ++j) {
      bf16x8 b = *(const bf16x8*)&Ws[(wc + j * 16 + r16) * AST + k0];
      acc[0][j] = __builtin_amdgcn_mfma_f32_16x16x32_bf16(a0, b, acc[0][j], 0, 0, 0);
      acc[1][j] = __builtin_amdgcn_mfma_f32_16x16x32_bf16(a1, b, acc[1][j], 0, 0, 0);
    }
  }

  __syncthreads();   // all As reads done; overwrite with h2
#pragma unroll
  for (int mi = 0; mi < 2; mi++) {
#pragma unroll
    for (int j = 0; j < 4; j++) {
      int col = wc + j * 16 + r16;
      float bv = bias[col];
      int rowb = wr + mi * 16 + (lane >> 4) * 4;
#pragma unroll
      for (int q = 0; q < 4; q++)
        As[(rowb + q) * AST + col] = f2bf(tanhf(acc[mi][j][q] + bv));
    }
  }
  __syncthreads();

  // head: wave w handles rows [w*16, w*16+16)
  f32x4 h = (f32x4){0.f, 0.f, 0.f, 0.f};
#pragma unroll
  for (int ks = 0; ks < 4; ++ks) {
    int k0 = ks * 32 + g8;
    bf16x8 a = *(const bf16x8*)&As[(w * 16 + r16) * AST + k0];
    bf16x8 b = *(const bf16x8*)&W3s[r16 * AST + k0];
    h = __builtin_amdgcn_mfma_f32_16x16x32_bf16(a, b, h, 0, 0, 0);
  }
  if (r16 < 10) {
    float bv = b3[r16];
    int rowb = w * 16 + (lane >> 4) * 4;
#pragma unroll
    for (int q = 0; q < 4; q++) {
      int node = node0 + rowb + q;
      if (node < n) out[(size_t)node * 10 + r16] = h[q] + bv;
    }
  }
}

extern "C" void kernel_launch(void* const* d_in, const int* in_sizes, int n_in,
                              void* d_out, int out_size, void* d_ws, size_t ws_size,
                              hipStream_t stream) {
  const float* x    = (const float*)d_in[0];
  const int*   esrc = (const int*)d_in[1];
  const int*   edst = (const int*)d_in[2];
  const float* W1   = (const float*)d_in[3];
  const float* b1   = (const float*)d_in[4];
  const float* W2   = (const float*)d_in[5];
  const float* b2   = (const float*)d_in[6];
  const float* W3   = (const float*)d_in[7];
  const float* b3   = (const float*)d_in[8];
  float* out = (float*)d_out;

  const int N = in_sizes[0] / DF;   // 100000
  const int E = in_sizes[1];        // 1600000

  const int nbuck   = (N + 255) >> 8;            // 391
  const int nblocks = (E + EPB - 1) / EPB;       // 782
  const int M = nbuck * nblocks;                 // ~306K

  // workspace layout
  char* ws = (char*)d_ws;
  int*  rowptr = (int*)ws;               // N+1
  int*  csr    = rowptr + (N + 1);       // E
  int*  histG  = csr + E;                // M
  int*  histE  = histG + M;              // M
  int*  bsums2 = histE + M;              // 1024
  uint* eb     = (uint*)(bsums2 + 1024); // E
  size_t off = (size_t)((char*)(eb + E) - ws);
  off = (off + 255) & ~(size_t)255;
  ushort* xb  = (ushort*)(ws + off);     off += (size_t)(N + 1) * DF * 2; off = (off + 255) & ~(size_t)255;
  ushort* Wt1 = (ushort*)(ws + off);     off += (size_t)DF * DF * 2;
  ushort* Wt2 = (ushort*)(ws + off);     off += (size_t)DF * DF * 2;
  ushort* W3t = (ushort*)(ws + off);     off += (size_t)16 * DF * 2; off = (off + 255) & ~(size_t)255;
  ushort* bufA = (ushort*)(ws + off);    off += (size_t)N * DF * 2; off = (off + 255) & ~(size_t)255;
  ushort* bufB = (ushort*)(ws + off);    // N+1 rows (zero row N)

  // prep (convert + 3 transposes + zero dummy rows in one launch)
  int n4 = N * DF / 4;
  int prep_total = n4 + 2 * DF * DF + 16 * DF + 32;
  prep_kernel<<<(prep_total + 255) / 256, 256, 0, stream>>>(
      x, xb, W1, Wt1, W2, Wt2, W3, W3t, xb + (size_t)N * DF, bufB + (size_t)N * DF, n4);

  // CSR build
  size_t lds_b = (size_t)nbuck * sizeof(int);
  bucket_hist_kernel<<<nblocks, 256, lds_b, stream>>>(edst, histG, E, nbuck, nblocks);
  int nb_m = (M + 1023) / 1024;
  scan1_kernel<<<nb_m, 256, 0, stream>>>(histG, histE, bsums2, M);
  scan2_kernel<<<1, 1024, 0, stream>>>(bsums2, nb_m);
  bucket_scatter_kernel<<<nblocks, 256, lds_b, stream>>>(esrc, edst, histE, bsums2, eb, E, nbuck, nblocks);
  bucket_sort_kernel<<<nbuck, 256, 0, stream>>>(eb, histE, bsums2, rowptr, csr, N, E, nbuck, nblocks);

  int agg_blocks = (N * 64 + 255) / 256;   // one wave per node
  int gemm_blocks = (N + 63) / 64;

  // layer 1
  aggregate_kernel<<<agg_blocks, 256, 0, stream>>>(xb, rowptr, csr, bufA, N);
  gemm_tanh_mfma<<<gemm_blocks, 256, 0, stream>>>(bufA, Wt1, b1, bufB, N);
  // layer 2 + head
  aggregate_kernel<<<agg_blocks, 256, 0, stream>>>(bufB, rowptr, csr, bufA, N);
  gemm2_head_mfma<<<gemm_blocks, 256, 0, stream>>>(bufA, Wt2, b2, W3t, b3, out, N);
}